// Round 1
// baseline (698.348 us; speedup 1.0000x reference)
//
#include <hip/hip_runtime.h>
#include <math.h>

typedef unsigned short ushort_t;
typedef __attribute__((ext_vector_type(8))) short bf16x8;
typedef __attribute__((ext_vector_type(4))) float f32x4;

#define TOKENS   4096
#define D_DIM    1024
#define E_NUM    8
#define F_DIM    4096

#define GLDS16(gp, lp) __builtin_amdgcn_global_load_lds( \
    (const __attribute__((address_space(1))) unsigned int*)(gp), \
    (__attribute__((address_space(3))) unsigned int*)(lp), 16, 0, 0)

__device__ __forceinline__ ushort_t f2bf(float f) {
    union { float f; unsigned u; } v; v.f = f;
    unsigned r = v.u + 0x7FFFu + ((v.u >> 16) & 1u);   // RNE
    return (ushort_t)(r >> 16);
}
__device__ __forceinline__ float bf2f(ushort_t u) {
    union { unsigned u; float f; } v; v.u = ((unsigned)u) << 16;
    return v.f;
}

// ---------------- fp32 -> bf16 bulk convert (8 elems/thread) ----------------
__global__ __launch_bounds__(256) void convert_kernel(
    const float* __restrict__ src, ushort_t* __restrict__ dst)
{
    size_t i = ((size_t)blockIdx.x * 256 + threadIdx.x) * 8;
    float4 a = *(const float4*)(src + i);
    float4 b = *(const float4*)(src + i + 4);
    union { ushort_t u[8]; uint4 v; } t;
    t.u[0] = f2bf(a.x); t.u[1] = f2bf(a.y); t.u[2] = f2bf(a.z); t.u[3] = f2bf(a.w);
    t.u[4] = f2bf(b.x); t.u[5] = f2bf(b.y); t.u[6] = f2bf(b.z); t.u[7] = f2bf(b.w);
    *(uint4*)(dst + i) = t.v;
}

// ---------------- Router: logits -> top2 -> gates -> per-expert position ----
__global__ __launch_bounds__(64) void router_kernel(
    const float* __restrict__ x, const float* __restrict__ Wr,
    const float* __restrict__ br,
    int* __restrict__ cnt, int* __restrict__ tok_e, int* __restrict__ tok_pos,
    float* __restrict__ tok_gate)
{
    int t = blockIdx.x;
    int lane = threadIdx.x;
    const float* xrow = x + (size_t)t * D_DIM;
    float acc[E_NUM];
#pragma unroll
    for (int e = 0; e < E_NUM; e++) acc[e] = 0.f;
    for (int d = lane; d < D_DIM; d += 64) {
        float xv = xrow[d];
#pragma unroll
        for (int e = 0; e < E_NUM; e++)
            acc[e] += xv * Wr[e * D_DIM + d];
    }
#pragma unroll
    for (int e = 0; e < E_NUM; e++) {
        float v = acc[e];
        for (int off = 32; off > 0; off >>= 1)
            v += __shfl_down(v, off, 64);
        acc[e] = v;
    }
    if (lane == 0) {
        float lg[E_NUM];
#pragma unroll
        for (int e = 0; e < E_NUM; e++) lg[e] = acc[e] + br[e];
        int e0 = 0;
#pragma unroll
        for (int e = 1; e < E_NUM; e++) if (lg[e] > lg[e0]) e0 = e;
        int e1 = (e0 == 0) ? 1 : 0;
#pragma unroll
        for (int e = 0; e < E_NUM; e++)
            if (e != e0 && lg[e] > lg[e1]) e1 = e;
        float g1 = expf(lg[e1] - lg[e0]);
        float denom = 1.f + g1;
        float gate0 = 1.f / denom, gate1 = g1 / denom;
        int p0 = atomicAdd(&cnt[e0], 1);
        int p1 = atomicAdd(&cnt[e1], 1);
        tok_e[t * 2] = e0;     tok_pos[t * 2] = p0;     tok_gate[t * 2] = gate0;
        tok_e[t * 2 + 1] = e1; tok_pos[t * 2 + 1] = p1; tok_gate[t * 2 + 1] = gate1;
    }
}

// ---------------- Padded per-expert offsets ---------------------------------
__global__ void offsets_kernel(const int* __restrict__ cnt,
                               int* __restrict__ pcount, int* __restrict__ poff)
{
    if (threadIdx.x == 0 && blockIdx.x == 0) {
        int off = 0;
        for (int e = 0; e < E_NUM; e++) {
            poff[e] = off;
            int pc = (cnt[e] + 127) & ~127;
            pcount[e] = pc;
            off += pc;
        }
        poff[E_NUM] = off;
    }
}

// ---------------- Gather x rows (fp32 -> bf16) into expert-compacted Xg -----
// One block per token: read the x row once, write both expert copies.
__global__ __launch_bounds__(256) void gather_kernel(
    const float* __restrict__ x,
    const int* __restrict__ tok_e, const int* __restrict__ tok_pos,
    const float* __restrict__ tok_gate, const int* __restrict__ poff,
    ushort_t* __restrict__ Xg, float* __restrict__ grow, int* __restrict__ rowof)
{
    int t = blockIdx.x;
    int ea = tok_e[t * 2], eb = tok_e[t * 2 + 1];
    int r0 = poff[ea] + tok_pos[t * 2];
    int r1 = poff[eb] + tok_pos[t * 2 + 1];
    if (threadIdx.x == 0) {
        grow[r0] = tok_gate[t * 2];     rowof[t * 2] = r0;
        grow[r1] = tok_gate[t * 2 + 1]; rowof[t * 2 + 1] = r1;
    }
    int i = threadIdx.x;                // 4 floats per thread
    float4 v = ((const float4*)(x + (size_t)t * D_DIM))[i];
    ushort4 o;
    o.x = f2bf(v.x); o.y = f2bf(v.y); o.z = f2bf(v.z); o.w = f2bf(v.w);
    *(ushort4*)(Xg + (size_t)r0 * D_DIM + i * 4) = o;
    *(ushort4*)(Xg + (size_t)r1 * D_DIM + i * 4) = o;
}

// ---------------- GEMM: C[m,n] = sum_k A[m,k]*B[n,k] (bf16, glds staging) ---
// Double-buffered LDS, 2-phase schedule (T3-minimum): issue next K-tile's
// global_load_lds BEFORE computing the current tile, one barrier per K-step.
// LDS layout is XOR-swizzled at the SOURCE: phys chunk c of row r holds global
// chunk c ^ (r&7). glds dest = wave-uniform base + lane*16 (m104/m108), so the
// swizzle must live in the global address, not the LDS address.
// ACT==0: H[row,n] = bf16(silu(C + b1[e,n]))
// ACT==1: O[row,n] = bf16(grow[row] * (C + b2[e,n]))
template <int ACT>
__global__ __launch_bounds__(256, 2) void gemm_kernel(
    const ushort_t* __restrict__ A,   // bf16 rows, ld = K
    const ushort_t* __restrict__ Bw,  // [E][N][K] bf16
    const float* __restrict__ bias,   // [E][N]
    const int* __restrict__ poff, const int* __restrict__ pcount,
    const float* __restrict__ grow,
    ushort_t* __restrict__ Cout,      // bf16 rows, ld = N
    int N, int K)
{
    __shared__ ushort_t As[2][128 * 64];
    __shared__ ushort_t Bs[2][128 * 64];

    int e = blockIdx.z;
    int pc = pcount[e];
    int mt = blockIdx.y;
    if (mt * 128 >= pc) return;
    int rowbase = poff[e] + mt * 128;
    int nbase = blockIdx.x * 128;

    int tid = threadIdx.x;
    int wave = tid >> 6;
    int lane = tid & 63;
    int wm = (wave & 1) * 64;
    int wn = (wave >> 1) * 64;
    int quad = lane >> 4;
    int l16 = lane & 15;
    int fswz = l16 & 7;               // fragment-read swizzle key

    int srow = lane >> 3;             // 0..7 within an 8-row group
    int soff = ((lane & 7) ^ srow) * 8;  // swizzled source chunk (elems)

    f32x4 acc[4][4];
#pragma unroll
    for (int i = 0; i < 4; i++)
#pragma unroll
        for (int j = 0; j < 4; j++) {
            f32x4 z = {0.f, 0.f, 0.f, 0.f};
            acc[i][j] = z;
        }

    const ushort_t* Ag = A + (size_t)rowbase * K;
    const ushort_t* Bg = Bw + ((size_t)e * N + nbase) * K;

    const int NT = K >> 6;            // number of 64-wide K tiles

    // -------- prologue: stage tile 0 into buffer 0 --------
#pragma unroll
    for (int it = 0; it < 4; it++) {
        int r = wave * 32 + it * 8;   // wave-uniform base row of 8-row group
        GLDS16(Ag + (size_t)(r + srow) * K + soff, &As[0][r * 64]);
        GLDS16(Bg + (size_t)(r + srow) * K + soff, &Bs[0][r * 64]);
    }
    __syncthreads();                  // drains vmcnt(0) -> tile 0 visible

    int cur = 0;
    for (int t = 0; t < NT; ++t) {
        // -------- issue next tile's staging FIRST (latency hides under MFMA)
        if (t + 1 < NT) {
            int k0n = (t + 1) << 6;
#pragma unroll
            for (int it = 0; it < 4; it++) {
                int r = wave * 32 + it * 8;
                GLDS16(Ag + (size_t)(r + srow) * K + k0n + soff, &As[cur ^ 1][r * 64]);
                GLDS16(Bg + (size_t)(r + srow) * K + k0n + soff, &Bs[cur ^ 1][r * 64]);
            }
        }
        // -------- compute current tile from buf[cur] --------
#pragma unroll
        for (int kk = 0; kk < 64; kk += 32) {
            int kc = kk >> 3;             // logical chunk base: 0 or 4
            bf16x8 af[4], bfr[4];
#pragma unroll
            for (int i = 0; i < 4; i++)
                af[i] = *(const bf16x8*)&As[cur][(wm + i * 16 + l16) * 64 +
                                                 (((quad + kc) ^ fswz) << 3)];
#pragma unroll
            for (int j = 0; j < 4; j++)
                bfr[j] = *(const bf16x8*)&Bs[cur][(wn + j * 16 + l16) * 64 +
                                                  (((quad + kc) ^ fswz) << 3)];
            __builtin_amdgcn_s_setprio(1);
#pragma unroll
            for (int i = 0; i < 4; i++)
#pragma unroll
                for (int j = 0; j < 4; j++)
                    acc[i][j] = __builtin_amdgcn_mfma_f32_16x16x32_bf16(
                        af[i], bfr[j], acc[i][j], 0, 0, 0);
            __builtin_amdgcn_s_setprio(0);
        }
        // one barrier per K-step: drains this wave's glds (vmcnt 0) + syncs
        __syncthreads();
        cur ^= 1;
    }

    // epilogue: D row = quad*4+r within 16-tile, col = l16
#pragma unroll
    for (int i = 0; i < 4; i++) {
#pragma unroll
        for (int j = 0; j < 4; j++) {
            int n = nbase + wn + j * 16 + l16;
            float bv = bias[(size_t)e * N + n];
#pragma unroll
            for (int r = 0; r < 4; r++) {
                int grow_row = rowbase + wm + i * 16 + quad * 4 + r;
                float v = acc[i][j][r] + bv;
                if (ACT == 0) {
                    v = v / (1.f + __expf(-v));           // SiLU
                } else {
                    v = grow[grow_row] * v;               // gate scale
                }
                Cout[(size_t)grow_row * N + n] = f2bf(v);
            }
        }
    }
}

// ---------------- Combine: y[t] = O[row0] + O[row1] -------------------------
__global__ __launch_bounds__(256) void combine_kernel(
    const ushort_t* __restrict__ O, const int* __restrict__ rowof,
    float* __restrict__ y)
{
    int t = blockIdx.x;
    int r0 = rowof[t * 2], r1 = rowof[t * 2 + 1];
    int d = threadIdx.x * 4;
    ushort4 a = *(const ushort4*)&O[(size_t)r0 * D_DIM + d];
    ushort4 b = *(const ushort4*)&O[(size_t)r1 * D_DIM + d];
    float4 o;
    o.x = bf2f(a.x) + bf2f(b.x);
    o.y = bf2f(a.y) + bf2f(b.y);
    o.z = bf2f(a.z) + bf2f(b.z);
    o.w = bf2f(a.w) + bf2f(b.w);
    *(float4*)&y[(size_t)t * D_DIM + d] = o;
}

extern "C" void kernel_launch(void* const* d_in, const int* in_sizes, int n_in,
                              void* d_out, int out_size, void* d_ws, size_t ws_size,
                              hipStream_t stream)
{
    (void)in_sizes; (void)n_in; (void)out_size; (void)ws_size;
    const float* x  = (const float*)d_in[0];
    const float* Wr = (const float*)d_in[1];
    const float* br = (const float*)d_in[2];
    const float* W1 = (const float*)d_in[3];
    const float* b1 = (const float*)d_in[4];
    const float* W2 = (const float*)d_in[5];
    const float* b2 = (const float*)d_in[6];
    float* y = (float*)d_out;

    char* ws = (char*)d_ws;
    int*   cnt      = (int*)(ws + 0);        // 8 ints
    int*   pcount   = (int*)(ws + 32);       // 8 ints
    int*   poff     = (int*)(ws + 64);       // 9 ints
    int*   tok_e    = (int*)(ws + 128);      // 8192 ints
    int*   tok_pos  = (int*)(ws + 32896);    // 8192 ints
    float* tok_gate = (float*)(ws + 65664);  // 8192 floats
    int*   rowof    = (int*)(ws + 98432);    // 8192 ints
    float* grow     = (float*)(ws + 131200); // 9216 floats
    // big buffers (256 KiB aligned start)
    ushort_t* Xg = (ushort_t*)(ws + 262144);                 // 9216x1024 bf16 (18,874,368 B)
    ushort_t* O  = Xg;                                       // aliased: Xg dead after GEMM1
    ushort_t* H  = (ushort_t*)(ws + 262144 + 18874368ull);   // 9216x4096 bf16 (75,497,472 B)
    ushort_t* Wb = (ushort_t*)(ws + 262144 + 18874368ull + 75497472ull); // 67,108,864 B, reused W1 then W2

    hipMemsetAsync(cnt, 0, 32, stream);
    hipMemsetAsync(Xg, 0, 18874368ull, stream);   // zero pad rows of Xg

    router_kernel<<<TOKENS, 64, 0, stream>>>(x, Wr, br, cnt, tok_e, tok_pos, tok_gate);
    offsets_kernel<<<1, 64, 0, stream>>>(cnt, pcount, poff);
    gather_kernel<<<TOKENS, 256, 0, stream>>>(x, tok_e, tok_pos, tok_gate, poff,
                                              Xg, grow, rowof);
    // W1 -> bf16, then GEMM1: [rows x 1024] @ W1[e]^T -> silu -> H [rows x 4096]
    convert_kernel<<<16384, 256, 0, stream>>>(W1, Wb);
    gemm_kernel<0><<<dim3(F_DIM / 128, 32, E_NUM), 256, 0, stream>>>(
        Xg, Wb, b1, poff, pcount, nullptr, H, F_DIM, D_DIM);
    // W2 -> bf16 (same buffer), then GEMM2: [rows x 4096] @ W2[e]^T -> gate -> O
    convert_kernel<<<16384, 256, 0, stream>>>(W2, Wb);
    gemm_kernel<1><<<dim3(D_DIM / 128, 32, E_NUM), 256, 0, stream>>>(
        H, Wb, b2, poff, pcount, grow, O, D_DIM, F_DIM);
    combine_kernel<<<TOKENS, 256, 0, stream>>>(O, rowof, y);
}

// Round 2
// 694.176 us; speedup vs baseline: 1.0060x; 1.0060x over previous
//
#include <hip/hip_runtime.h>
#include <math.h>

typedef unsigned short ushort_t;
typedef __attribute__((ext_vector_type(8))) short bf16x8;
typedef __attribute__((ext_vector_type(4))) float f32x4;

#define TOKENS   4096
#define D_DIM    1024
#define E_NUM    8
#define F_DIM    4096

#define GLDS16(gp, lp) __builtin_amdgcn_global_load_lds( \
    (const __attribute__((address_space(1))) unsigned int*)(gp), \
    (__attribute__((address_space(3))) unsigned int*)(lp), 16, 0, 0)

__device__ __forceinline__ ushort_t f2bf(float f) {
    union { float f; unsigned u; } v; v.f = f;
    unsigned r = v.u + 0x7FFFu + ((v.u >> 16) & 1u);   // RNE
    return (ushort_t)(r >> 16);
}
__device__ __forceinline__ float bf2f(ushort_t u) {
    union { unsigned u; float f; } v; v.u = ((unsigned)u) << 16;
    return v.f;
}

// ---------------- fp32 -> bf16 bulk convert (8 elems/thread) ----------------
__global__ __launch_bounds__(256) void convert_kernel(
    const float* __restrict__ src, ushort_t* __restrict__ dst)
{
    size_t i = ((size_t)blockIdx.x * 256 + threadIdx.x) * 8;
    float4 a = *(const float4*)(src + i);
    float4 b = *(const float4*)(src + i + 4);
    union { ushort_t u[8]; uint4 v; } t;
    t.u[0] = f2bf(a.x); t.u[1] = f2bf(a.y); t.u[2] = f2bf(a.z); t.u[3] = f2bf(a.w);
    t.u[4] = f2bf(b.x); t.u[5] = f2bf(b.y); t.u[6] = f2bf(b.z); t.u[7] = f2bf(b.w);
    *(uint4*)(dst + i) = t.v;
}

// ---------------- Router: logits -> top2 -> gates -> per-expert position ----
__global__ __launch_bounds__(64) void router_kernel(
    const float* __restrict__ x, const float* __restrict__ Wr,
    const float* __restrict__ br,
    int* __restrict__ cnt, int* __restrict__ tok_e, int* __restrict__ tok_pos,
    float* __restrict__ tok_gate)
{
    int t = blockIdx.x;
    int lane = threadIdx.x;
    const float* xrow = x + (size_t)t * D_DIM;
    float acc[E_NUM];
#pragma unroll
    for (int e = 0; e < E_NUM; e++) acc[e] = 0.f;
    for (int d = lane; d < D_DIM; d += 64) {
        float xv = xrow[d];
#pragma unroll
        for (int e = 0; e < E_NUM; e++)
            acc[e] += xv * Wr[e * D_DIM + d];
    }
#pragma unroll
    for (int e = 0; e < E_NUM; e++) {
        float v = acc[e];
        for (int off = 32; off > 0; off >>= 1)
            v += __shfl_down(v, off, 64);
        acc[e] = v;
    }
    if (lane == 0) {
        float lg[E_NUM];
#pragma unroll
        for (int e = 0; e < E_NUM; e++) lg[e] = acc[e] + br[e];
        int e0 = 0;
#pragma unroll
        for (int e = 1; e < E_NUM; e++) if (lg[e] > lg[e0]) e0 = e;
        int e1 = (e0 == 0) ? 1 : 0;
#pragma unroll
        for (int e = 0; e < E_NUM; e++)
            if (e != e0 && lg[e] > lg[e1]) e1 = e;
        float g1 = expf(lg[e1] - lg[e0]);
        float denom = 1.f + g1;
        float gate0 = 1.f / denom, gate1 = g1 / denom;
        int p0 = atomicAdd(&cnt[e0], 1);
        int p1 = atomicAdd(&cnt[e1], 1);
        tok_e[t * 2] = e0;     tok_pos[t * 2] = p0;     tok_gate[t * 2] = gate0;
        tok_e[t * 2 + 1] = e1; tok_pos[t * 2 + 1] = p1; tok_gate[t * 2 + 1] = gate1;
    }
}

// ---------------- Padded per-expert offsets ---------------------------------
__global__ void offsets_kernel(const int* __restrict__ cnt,
                               int* __restrict__ pcount, int* __restrict__ poff)
{
    if (threadIdx.x == 0 && blockIdx.x == 0) {
        int off = 0;
        for (int e = 0; e < E_NUM; e++) {
            poff[e] = off;
            int pc = (cnt[e] + 127) & ~127;
            pcount[e] = pc;
            off += pc;
        }
        poff[E_NUM] = off;
    }
}

// ---------------- Gather x rows (fp32 -> bf16) into expert-compacted Xg -----
// One block per token: read the x row once, write both expert copies.
__global__ __launch_bounds__(256) void gather_kernel(
    const float* __restrict__ x,
    const int* __restrict__ tok_e, const int* __restrict__ tok_pos,
    const float* __restrict__ tok_gate, const int* __restrict__ poff,
    ushort_t* __restrict__ Xg, float* __restrict__ grow, int* __restrict__ rowof)
{
    int t = blockIdx.x;
    int ea = tok_e[t * 2], eb = tok_e[t * 2 + 1];
    int r0 = poff[ea] + tok_pos[t * 2];
    int r1 = poff[eb] + tok_pos[t * 2 + 1];
    if (threadIdx.x == 0) {
        grow[r0] = tok_gate[t * 2];     rowof[t * 2] = r0;
        grow[r1] = tok_gate[t * 2 + 1]; rowof[t * 2 + 1] = r1;
    }
    int i = threadIdx.x;                // 4 floats per thread
    float4 v = ((const float4*)(x + (size_t)t * D_DIM))[i];
    ushort4 o;
    o.x = f2bf(v.x); o.y = f2bf(v.y); o.z = f2bf(v.z); o.w = f2bf(v.w);
    *(ushort4*)(Xg + (size_t)r0 * D_DIM + i * 4) = o;
    *(ushort4*)(Xg + (size_t)r1 * D_DIM + i * 4) = o;
}

// ---------------- 256x256x64 8-wave 4-phase GEMM (m248-style) ---------------
// C[m,n] = sum_k A[m,k]*B[n,k], bf16 in, fp32 acc.
// 512 threads = 8 waves as 2M x 4N; per-wave output 128x64 (acc 8x4 of 16x16).
// LDS (dynamic, 128 KiB): As[2][256*64], Bs[2][256*64], source-XOR-swizzled
// (phys chunk c of row r holds global chunk c^(r&7); glds dest stays linear).
// Schedule per K-tile (T3+T4+T5): 4 phases; phase p stages half-tile p of the
// NEXT K-tile (raw s_barrier, no vmcnt drain); ONE counted vmcnt(2) per tile
// at phase 0 (after issuing its stage, so the 2 newest loads stay in flight).
// Phase 0 reads all 8 B-frags (held in regs for the tile) + A-rows 0..1;
// phases 1-3 read A-rows 2p..2p+1. 16 MFMA per phase under setprio(1).
// ACT==0: silu(C + b1);  ACT==1: grow[row] * (C + b2). Stores guarded to the
// expert's padded row range (256-tiles may overrun into the next expert).
template <int ACT>
__global__ __launch_bounds__(512, 1) void gemm256_kernel(
    const ushort_t* __restrict__ A,   // bf16 rows, ld = K
    const ushort_t* __restrict__ Bw,  // [E][N][K] bf16
    const float* __restrict__ bias,   // [E][N]
    const int* __restrict__ poff, const int* __restrict__ pcount,
    const float* __restrict__ grow,
    ushort_t* __restrict__ Cout,      // bf16 rows, ld = N
    int N, int K)
{
    extern __shared__ ushort_t lds[];   // 131072 B: As[2][16384], Bs[2][16384]

    // ---- bijective XCD swizzle of the flat block id (nwg % 8 == 0) ----
    int nwg  = gridDim.x * gridDim.y * gridDim.z;
    int flat = blockIdx.x + gridDim.x * (blockIdx.y + gridDim.y * blockIdx.z);
    int swz  = (flat & 7) * (nwg >> 3) + (flat >> 3);
    int bx   = swz % gridDim.x;
    int rest = swz / gridDim.x;
    int by   = rest % gridDim.y;
    int e    = rest / gridDim.y;

    int pc = pcount[e];
    if (by * 256 >= pc) return;
    int rowbase = poff[e] + by * 256;
    int nbase   = bx * 256;

    int tid  = threadIdx.x;
    int wid  = tid >> 6;              // 0..7
    int lane = tid & 63;
    int wm   = (wid >> 2) * 128;      // wave M offset (0 or 128)
    int wn   = (wid & 3) * 64;        // wave N offset (0,64,128,192)
    int quad = lane >> 4;
    int l16  = lane & 15;
    int fswz = l16 & 7;               // fragment-read swizzle key

    int srow = lane >> 3;             // 0..7 within an 8-row group
    int soff = ((lane & 7) ^ srow) * 8;  // swizzled source chunk (elems)

    const ushort_t* Ag = A + (size_t)rowbase * K;
    const ushort_t* Bg = Bw + ((size_t)e * N + nbase) * K;

    f32x4 acc[8][4];
#pragma unroll
    for (int i = 0; i < 8; i++)
#pragma unroll
        for (int j = 0; j < 4; j++) {
            f32x4 z = {0.f, 0.f, 0.f, 0.f};
            acc[i][j] = z;
        }

    // ---- staging helper: half-tile h (0,1 = A rows h*128; 2,3 = B rows) ----
    // 2 glds per thread: row groups {wid*8, 64+wid*8} within the half.
    auto stage_half = [&](int buf, int h, int k0) {
        if (h < 2) {
            int rb = h * 128;
            GLDS16(Ag + (size_t)(rb + wid * 8 + srow) * K + k0 + soff,
                   &lds[(size_t)buf * 16384 + (rb + wid * 8) * 64]);
            GLDS16(Ag + (size_t)(rb + 64 + wid * 8 + srow) * K + k0 + soff,
                   &lds[(size_t)buf * 16384 + (rb + 64 + wid * 8) * 64]);
        } else {
            int rb = (h - 2) * 128;
            GLDS16(Bg + (size_t)(rb + wid * 8 + srow) * K + k0 + soff,
                   &lds[32768 + (size_t)buf * 16384 + (rb + wid * 8) * 64]);
            GLDS16(Bg + (size_t)(rb + 64 + wid * 8 + srow) * K + k0 + soff,
                   &lds[32768 + (size_t)buf * 16384 + (rb + 64 + wid * 8) * 64]);
        }
    };

    const int NT = K >> 6;

    // -------- prologue: stage tile 0 (4 half-tiles) into buffer 0 --------
#pragma unroll
    for (int h = 0; h < 4; h++) stage_half(0, h, 0);

    int c = 0;
    for (int t = 0; t < NT; ++t) {
        const ushort_t* As_c = lds + c * 16384;
        const ushort_t* Bs_c = lds + 32768 + c * 16384;
        int k1 = (t + 1) << 6;
        bool more = (t + 1) < NT;

        // ---------------- phase 0 ----------------
        if (more) {
            stage_half(c ^ 1, 0, k1);
            asm volatile("s_waitcnt vmcnt(2)" ::: "memory");
        } else {
            asm volatile("s_waitcnt vmcnt(0)" ::: "memory");
        }
        asm volatile("s_barrier" ::: "memory");   // buf c fully staged, all waves

        bf16x8 bfrag[4][2];
#pragma unroll
        for (int j = 0; j < 4; j++)
#pragma unroll
            for (int kh = 0; kh < 2; kh++)
                bfrag[j][kh] = *(const bf16x8*)&Bs_c[(wn + j * 16 + l16) * 64 +
                                                     (((quad + kh * 4) ^ fswz) << 3)];
        {
            bf16x8 afr[2][2];
#pragma unroll
            for (int i = 0; i < 2; i++)
#pragma unroll
                for (int kh = 0; kh < 2; kh++)
                    afr[i][kh] = *(const bf16x8*)&As_c[(wm + i * 16 + l16) * 64 +
                                                        (((quad + kh * 4) ^ fswz) << 3)];
            __builtin_amdgcn_s_setprio(1);
#pragma unroll
            for (int i = 0; i < 2; i++)
#pragma unroll
                for (int j = 0; j < 4; j++) {
                    acc[i][j] = __builtin_amdgcn_mfma_f32_16x16x32_bf16(
                        afr[i][0], bfrag[j][0], acc[i][j], 0, 0, 0);
                    acc[i][j] = __builtin_amdgcn_mfma_f32_16x16x32_bf16(
                        afr[i][1], bfrag[j][1], acc[i][j], 0, 0, 0);
                }
            __builtin_amdgcn_s_setprio(0);
        }
        asm volatile("s_barrier" ::: "memory");

        // ---------------- phases 1..3 ----------------
#pragma unroll
        for (int p = 1; p < 4; ++p) {
            if (more) stage_half(c ^ 1, p, k1);
            bf16x8 afr[2][2];
#pragma unroll
            for (int i = 0; i < 2; i++)
#pragma unroll
                for (int kh = 0; kh < 2; kh++)
                    afr[i][kh] = *(const bf16x8*)&As_c[(wm + (2 * p + i) * 16 + l16) * 64 +
                                                        (((quad + kh * 4) ^ fswz) << 3)];
            asm volatile("s_barrier" ::: "memory");   // pre-MFMA phase align
            __builtin_amdgcn_s_setprio(1);
#pragma unroll
            for (int i = 0; i < 2; i++)
#pragma unroll
                for (int j = 0; j < 4; j++) {
                    acc[2 * p + i][j] = __builtin_amdgcn_mfma_f32_16x16x32_bf16(
                        afr[i][0], bfrag[j][0], acc[2 * p + i][j], 0, 0, 0);
                    acc[2 * p + i][j] = __builtin_amdgcn_mfma_f32_16x16x32_bf16(
                        afr[i][1], bfrag[j][1], acc[2 * p + i][j], 0, 0, 0);
                }
            __builtin_amdgcn_s_setprio(0);
            asm volatile("s_barrier" ::: "memory");
        }
        c ^= 1;
    }

    // -------- epilogue: store with row guard (grouped 256-tile overrun) -----
    int rowlim = poff[e] + pc;
#pragma unroll
    for (int i = 0; i < 8; i++) {
        float gv[4];
        if (ACT == 1) {
#pragma unroll
            for (int r = 0; r < 4; r++)
                gv[r] = grow[rowbase + wm + i * 16 + quad * 4 + r];
        }
#pragma unroll
        for (int j = 0; j < 4; j++) {
            int n = nbase + wn + j * 16 + l16;
            float bv = bias[(size_t)e * N + n];
#pragma unroll
            for (int r = 0; r < 4; r++) {
                int row = rowbase + wm + i * 16 + quad * 4 + r;
                if (row < rowlim) {
                    float v = acc[i][j][r] + bv;
                    if (ACT == 0) {
                        v = v / (1.f + __expf(-v));           // SiLU
                    } else {
                        v = gv[r] * v;                        // gate scale
                    }
                    Cout[(size_t)row * N + n] = f2bf(v);
                }
            }
        }
    }
}

// ---------------- Combine: y[t] = O[row0] + O[row1] -------------------------
__global__ __launch_bounds__(256) void combine_kernel(
    const ushort_t* __restrict__ O, const int* __restrict__ rowof,
    float* __restrict__ y)
{
    int t = blockIdx.x;
    int r0 = rowof[t * 2], r1 = rowof[t * 2 + 1];
    int d = threadIdx.x * 4;
    ushort4 a = *(const ushort4*)&O[(size_t)r0 * D_DIM + d];
    ushort4 b = *(const ushort4*)&O[(size_t)r1 * D_DIM + d];
    float4 o;
    o.x = bf2f(a.x) + bf2f(b.x);
    o.y = bf2f(a.y) + bf2f(b.y);
    o.z = bf2f(a.z) + bf2f(b.z);
    o.w = bf2f(a.w) + bf2f(b.w);
    *(float4*)&y[(size_t)t * D_DIM + d] = o;
}

extern "C" void kernel_launch(void* const* d_in, const int* in_sizes, int n_in,
                              void* d_out, int out_size, void* d_ws, size_t ws_size,
                              hipStream_t stream)
{
    (void)in_sizes; (void)n_in; (void)out_size; (void)ws_size;
    const float* x  = (const float*)d_in[0];
    const float* Wr = (const float*)d_in[1];
    const float* br = (const float*)d_in[2];
    const float* W1 = (const float*)d_in[3];
    const float* b1 = (const float*)d_in[4];
    const float* W2 = (const float*)d_in[5];
    const float* b2 = (const float*)d_in[6];
    float* y = (float*)d_out;

    char* ws = (char*)d_ws;
    int*   cnt      = (int*)(ws + 0);        // 8 ints
    int*   pcount   = (int*)(ws + 32);       // 8 ints
    int*   poff     = (int*)(ws + 64);       // 9 ints
    int*   tok_e    = (int*)(ws + 128);      // 8192 ints
    int*   tok_pos  = (int*)(ws + 32896);    // 8192 ints
    float* tok_gate = (float*)(ws + 65664);  // 8192 floats
    int*   rowof    = (int*)(ws + 98432);    // 8192 ints
    float* grow     = (float*)(ws + 131200); // 9216 floats
    // big buffers (256 KiB aligned start)
    ushort_t* Xg = (ushort_t*)(ws + 262144);                 // 9216x1024 bf16 (18,874,368 B)
    ushort_t* O  = Xg;                                       // aliased: Xg dead after GEMM1
    ushort_t* H  = (ushort_t*)(ws + 262144 + 18874368ull);   // 9216x4096 bf16 (75,497,472 B)
    ushort_t* Wb = (ushort_t*)(ws + 262144 + 18874368ull + 75497472ull); // 67,108,864 B, reused W1 then W2

    // allow 128 KiB dynamic LDS for the 256^2 GEMM (host-side attr, not
    // stream-ordered -> graph-capture safe; done once)
    static int lds_attr_done = 0;
    if (!lds_attr_done) {
        hipFuncSetAttribute(reinterpret_cast<const void*>(&gemm256_kernel<0>),
                            hipFuncAttributeMaxDynamicSharedMemorySize, 131072);
        hipFuncSetAttribute(reinterpret_cast<const void*>(&gemm256_kernel<1>),
                            hipFuncAttributeMaxDynamicSharedMemorySize, 131072);
        lds_attr_done = 1;
    }

    hipMemsetAsync(cnt, 0, 32, stream);
    hipMemsetAsync(Xg, 0, 18874368ull, stream);   // zero pad rows of Xg

    router_kernel<<<TOKENS, 64, 0, stream>>>(x, Wr, br, cnt, tok_e, tok_pos, tok_gate);
    offsets_kernel<<<1, 64, 0, stream>>>(cnt, pcount, poff);
    gather_kernel<<<TOKENS, 256, 0, stream>>>(x, tok_e, tok_pos, tok_gate, poff,
                                              Xg, grow, rowof);
    // W1 -> bf16, then GEMM1: [rows x 1024] @ W1[e]^T -> silu -> H [rows x 4096]
    convert_kernel<<<16384, 256, 0, stream>>>(W1, Wb);
    gemm256_kernel<0><<<dim3(F_DIM / 256, 16, E_NUM), 512, 131072, stream>>>(
        Xg, Wb, b1, poff, pcount, nullptr, H, F_DIM, D_DIM);
    // W2 -> bf16 (same buffer), then GEMM2: [rows x 4096] @ W2[e]^T -> gate -> O
    convert_kernel<<<16384, 256, 0, stream>>>(W2, Wb);
    gemm256_kernel<1><<<dim3(D_DIM / 256, 16, E_NUM), 512, 131072, stream>>>(
        H, Wb, b2, poff, pcount, grow, O, D_DIM, F_DIM);
    combine_kernel<<<TOKENS, 256, 0, stream>>>(O, rowof, y);
}

// Round 3
// 691.739 us; speedup vs baseline: 1.0096x; 1.0035x over previous
//
#include <hip/hip_runtime.h>
#include <math.h>

typedef unsigned short ushort_t;
typedef __attribute__((ext_vector_type(8))) short bf16x8;
typedef __attribute__((ext_vector_type(4))) float f32x4;

#define TOKENS   4096
#define D_DIM    1024
#define E_NUM    8
#define F_DIM    4096

#define GLDS16(gp, lp) __builtin_amdgcn_global_load_lds( \
    (const __attribute__((address_space(1))) unsigned int*)(gp), \
    (__attribute__((address_space(3))) unsigned int*)(lp), 16, 0, 0)

__device__ __forceinline__ ushort_t f2bf(float f) {
    union { float f; unsigned u; } v; v.f = f;
    unsigned r = v.u + 0x7FFFu + ((v.u >> 16) & 1u);   // RNE
    return (ushort_t)(r >> 16);
}
__device__ __forceinline__ float bf2f(ushort_t u) {
    union { unsigned u; float f; } v; v.u = ((unsigned)u) << 16;
    return v.f;
}

// ---------------- Router: logits -> top2 -> gates -> per-expert position ----
__global__ __launch_bounds__(64) void router_kernel(
    const float* __restrict__ x, const float* __restrict__ Wr,
    const float* __restrict__ br,
    int* __restrict__ cnt, int* __restrict__ tok_e, int* __restrict__ tok_pos,
    float* __restrict__ tok_gate)
{
    int t = blockIdx.x;
    int lane = threadIdx.x;
    const float* xrow = x + (size_t)t * D_DIM;
    float acc[E_NUM];
#pragma unroll
    for (int e = 0; e < E_NUM; e++) acc[e] = 0.f;
    for (int d = lane; d < D_DIM; d += 64) {
        float xv = xrow[d];
#pragma unroll
        for (int e = 0; e < E_NUM; e++)
            acc[e] += xv * Wr[e * D_DIM + d];
    }
#pragma unroll
    for (int e = 0; e < E_NUM; e++) {
        float v = acc[e];
        for (int off = 32; off > 0; off >>= 1)
            v += __shfl_down(v, off, 64);
        acc[e] = v;
    }
    if (lane == 0) {
        float lg[E_NUM];
#pragma unroll
        for (int e = 0; e < E_NUM; e++) lg[e] = acc[e] + br[e];
        int e0 = 0;
#pragma unroll
        for (int e = 1; e < E_NUM; e++) if (lg[e] > lg[e0]) e0 = e;
        int e1 = (e0 == 0) ? 1 : 0;
#pragma unroll
        for (int e = 0; e < E_NUM; e++)
            if (e != e0 && lg[e] > lg[e1]) e1 = e;
        float g1 = expf(lg[e1] - lg[e0]);
        float denom = 1.f + g1;
        float gate0 = 1.f / denom, gate1 = g1 / denom;
        int p0 = atomicAdd(&cnt[e0], 1);
        int p1 = atomicAdd(&cnt[e1], 1);
        tok_e[t * 2] = e0;     tok_pos[t * 2] = p0;     tok_gate[t * 2] = gate0;
        tok_e[t * 2 + 1] = e1; tok_pos[t * 2 + 1] = p1; tok_gate[t * 2 + 1] = gate1;
    }
}

// ---------------- Gather x rows (fp32 -> bf16) into expert-compacted Xg -----
// One block per token: read the x row once, write both expert copies.
// Padded per-expert offsets recomputed inline from cnt (uniform scalar loop).
__global__ __launch_bounds__(256) void gather_kernel(
    const float* __restrict__ x, const int* __restrict__ cnt,
    const int* __restrict__ tok_e, const int* __restrict__ tok_pos,
    const float* __restrict__ tok_gate,
    ushort_t* __restrict__ Xg, float* __restrict__ grow, int* __restrict__ rowof)
{
    int t = blockIdx.x;
    int ea = tok_e[t * 2], eb = tok_e[t * 2 + 1];
    int off = 0, pa = 0, pb = 0;
#pragma unroll
    for (int q = 0; q < E_NUM; q++) {
        if (q == ea) pa = off;
        if (q == eb) pb = off;
        off += (cnt[q] + 127) & ~127;
    }
    int r0 = pa + tok_pos[t * 2];
    int r1 = pb + tok_pos[t * 2 + 1];
    if (threadIdx.x == 0) {
        grow[r0] = tok_gate[t * 2];     rowof[t * 2] = r0;
        grow[r1] = tok_gate[t * 2 + 1]; rowof[t * 2 + 1] = r1;
    }
    int i = threadIdx.x;                // 4 floats per thread
    float4 v = ((const float4*)(x + (size_t)t * D_DIM))[i];
    ushort4 o;
    o.x = f2bf(v.x); o.y = f2bf(v.y); o.z = f2bf(v.z); o.w = f2bf(v.w);
    *(ushort4*)(Xg + (size_t)r0 * D_DIM + i * 4) = o;
    *(ushort4*)(Xg + (size_t)r1 * D_DIM + i * 4) = o;
}

// ---------------- GEMM: C[m,n] = sum_k A[m,k]*B[n,k] ------------------------
// A: bf16, staged via global_load_lds (source-XOR-swizzled: phys chunk c of
// row r holds global chunk c^(r&7); glds dest stays linear — m104/m108).
// B: fp32 weights, reg-staged (float4 loads -> v_cvt_pk_bf16_f32 RNE ->
// ds_write_b128 at the swizzled chunk) — fuses the old convert_kernel away.
// Grid: x = m-tile (fastest), y = n-tile, z = expert, + chunked XCD swizzle so
// blocks sharing a B panel are consecutive on the same XCD's L2.
// ACT==0: H[row,n] = bf16(silu(C + b1[e,n]))
// ACT==1: O[row,n] = bf16(grow[row] * (C + b2[e,n]))
template <int ACT>
__global__ __launch_bounds__(256, 4) void gemm_kernel(
    const ushort_t* __restrict__ A,   // bf16 rows, ld = K
    const float* __restrict__ Bw,     // [E][N][K] fp32
    const float* __restrict__ bias,   // [E][N]
    const int* __restrict__ cnt,
    const float* __restrict__ grow,
    ushort_t* __restrict__ Cout,      // bf16 rows, ld = N
    int N, int K)
{
    __shared__ ushort_t As[128 * 64];
    __shared__ ushort_t Bs[128 * 64];

    // ---- chunked XCD swizzle (nwg % 8 == 0): same-(n,e) blocks contiguous
    // within one XCD chunk -> shared B panel stays in that XCD's L2.
    int nwg  = gridDim.x * gridDim.y * gridDim.z;
    int flat = blockIdx.x + gridDim.x * (blockIdx.y + gridDim.y * blockIdx.z);
    int swz  = (flat & 7) * (nwg >> 3) + (flat >> 3);
    int mt   = swz % gridDim.x;                 // m-tile (fastest)
    int rest = swz / gridDim.x;
    int nt   = rest % gridDim.y;                // n-tile
    int e    = rest / gridDim.y;                // expert

    // padded per-expert offsets from cnt (uniform scalar loop)
    int rowbase = 0, pc = 0;
#pragma unroll
    for (int q = 0; q < E_NUM; q++) {
        int p = (cnt[q] + 127) & ~127;
        if (q < e) rowbase += p;
        if (q == e) pc = p;
    }
    if (mt * 128 >= pc) return;
    rowbase += mt * 128;
    int nbase = nt * 128;

    int tid = threadIdx.x;
    int wave = tid >> 6;
    int lane = tid & 63;
    int wm = (wave & 1) * 64;
    int wn = (wave >> 1) * 64;
    int quad = lane >> 4;
    int l16 = lane & 15;
    int fswz = l16 & 7;               // fragment-read swizzle key

    int srow = lane >> 3;             // 0..7 within an 8-row group
    int soff = ((lane & 7) ^ srow) * 8;  // swizzled A source chunk (elems)

    int brow = tid >> 3;              // 0..31: B staging row within 32-group
    int bchk = tid & 7;               // B staging chunk (8 elems)
    int bphys[4];
#pragma unroll
    for (int g = 0; g < 4; g++) {
        int r = g * 32 + brow;
        bphys[g] = r * 64 + ((bchk ^ (r & 7)) << 3);
    }

    f32x4 acc[4][4];
#pragma unroll
    for (int i = 0; i < 4; i++)
#pragma unroll
        for (int j = 0; j < 4; j++) {
            f32x4 z = {0.f, 0.f, 0.f, 0.f};
            acc[i][j] = z;
        }

    const ushort_t* Ag = A + (size_t)rowbase * K;
    const float*    Bg = Bw + ((size_t)e * N + nbase) * K;

    for (int k0 = 0; k0 < K; k0 += 64) {
        __syncthreads();              // WAR: prev compute done reading LDS
        // ---- A: async glds, 4 x 8-row groups per wave ----
#pragma unroll
        for (int it = 0; it < 4; it++) {
            int r = wave * 32 + it * 8;   // wave-uniform base row
            GLDS16(Ag + (size_t)(r + srow) * K + k0 + soff, &As[r * 64]);
        }
        // ---- B: fp32 -> bf16 reg staging (issue all loads, then cvt+write)
        float4 bl[4][2];
#pragma unroll
        for (int g = 0; g < 4; g++) {
            const float* src = Bg + (size_t)(g * 32 + brow) * K + k0 + bchk * 8;
            bl[g][0] = *(const float4*)(src);
            bl[g][1] = *(const float4*)(src + 4);
        }
#pragma unroll
        for (int g = 0; g < 4; g++) {
            unsigned u0, u1, u2, u3;
            asm("v_cvt_pk_bf16_f32 %0, %1, %2" : "=v"(u0) : "v"(bl[g][0].x), "v"(bl[g][0].y));
            asm("v_cvt_pk_bf16_f32 %0, %1, %2" : "=v"(u1) : "v"(bl[g][0].z), "v"(bl[g][0].w));
            asm("v_cvt_pk_bf16_f32 %0, %1, %2" : "=v"(u2) : "v"(bl[g][1].x), "v"(bl[g][1].y));
            asm("v_cvt_pk_bf16_f32 %0, %1, %2" : "=v"(u3) : "v"(bl[g][1].z), "v"(bl[g][1].w));
            uint4 w; w.x = u0; w.y = u1; w.z = u2; w.w = u3;
            *(uint4*)&Bs[bphys[g]] = w;
        }
        __syncthreads();              // drains glds (vmcnt) + ds_writes (lgkm)
        // ---- compute ----
#pragma unroll
        for (int kk = 0; kk < 64; kk += 32) {
            int kc = kk >> 3;             // logical chunk base: 0 or 4
            bf16x8 af[4], bfr[4];
#pragma unroll
            for (int i = 0; i < 4; i++)
                af[i] = *(const bf16x8*)&As[(wm + i * 16 + l16) * 64 +
                                            (((quad + kc) ^ fswz) << 3)];
#pragma unroll
            for (int j = 0; j < 4; j++)
                bfr[j] = *(const bf16x8*)&Bs[(wn + j * 16 + l16) * 64 +
                                             (((quad + kc) ^ fswz) << 3)];
#pragma unroll
            for (int i = 0; i < 4; i++)
#pragma unroll
                for (int j = 0; j < 4; j++)
                    acc[i][j] = __builtin_amdgcn_mfma_f32_16x16x32_bf16(
                        af[i], bfr[j], acc[i][j], 0, 0, 0);
        }
    }

    // epilogue: D row = quad*4+r within 16-tile, col = l16
#pragma unroll
    for (int i = 0; i < 4; i++) {
#pragma unroll
        for (int j = 0; j < 4; j++) {
            int n = nbase + wn + j * 16 + l16;
            float bv = bias[(size_t)e * N + n];
#pragma unroll
            for (int r = 0; r < 4; r++) {
                int grow_row = rowbase + wm + i * 16 + quad * 4 + r;
                float v = acc[i][j][r] + bv;
                if (ACT == 0) {
                    v = v / (1.f + __expf(-v));           // SiLU
                } else {
                    v = grow[grow_row] * v;               // gate scale
                }
                Cout[(size_t)grow_row * N + n] = f2bf(v);
            }
        }
    }
}

// ---------------- Combine: y[t] = O[row0] + O[row1] -------------------------
__global__ __launch_bounds__(256) void combine_kernel(
    const ushort_t* __restrict__ O, const int* __restrict__ rowof,
    float* __restrict__ y)
{
    int t = blockIdx.x;
    int r0 = rowof[t * 2], r1 = rowof[t * 2 + 1];
    int d = threadIdx.x * 4;
    ushort4 a = *(const ushort4*)&O[(size_t)r0 * D_DIM + d];
    ushort4 b = *(const ushort4*)&O[(size_t)r1 * D_DIM + d];
    float4 o;
    o.x = bf2f(a.x) + bf2f(b.x);
    o.y = bf2f(a.y) + bf2f(b.y);
    o.z = bf2f(a.z) + bf2f(b.z);
    o.w = bf2f(a.w) + bf2f(b.w);
    *(float4*)&y[(size_t)t * D_DIM + d] = o;
}

extern "C" void kernel_launch(void* const* d_in, const int* in_sizes, int n_in,
                              void* d_out, int out_size, void* d_ws, size_t ws_size,
                              hipStream_t stream)
{
    (void)in_sizes; (void)n_in; (void)out_size; (void)ws_size;
    const float* x  = (const float*)d_in[0];
    const float* Wr = (const float*)d_in[1];
    const float* br = (const float*)d_in[2];
    const float* W1 = (const float*)d_in[3];
    const float* b1 = (const float*)d_in[4];
    const float* W2 = (const float*)d_in[5];
    const float* b2 = (const float*)d_in[6];
    float* y = (float*)d_out;

    char* ws = (char*)d_ws;
    int*   cnt      = (int*)(ws + 0);        // 8 ints
    int*   tok_e    = (int*)(ws + 128);      // 8192 ints
    int*   tok_pos  = (int*)(ws + 32896);    // 8192 ints
    float* tok_gate = (float*)(ws + 65664);  // 8192 floats
    int*   rowof    = (int*)(ws + 98432);    // 8192 ints
    float* grow     = (float*)(ws + 131200); // 9216 floats
    // big buffers (256 KiB aligned start)
    ushort_t* Xg = (ushort_t*)(ws + 262144);                 // 9216x1024 bf16 (18,874,368 B)
    ushort_t* O  = Xg;                                       // aliased: Xg dead after GEMM1
    ushort_t* H  = (ushort_t*)(ws + 262144 + 18874368ull);   // 9216x4096 bf16 (75,497,472 B)

    hipMemsetAsync(cnt, 0, 32, stream);
    // NOTE: no Xg pad-row memset — pad A rows only affect pad output rows
    // (MFMA row independence), which are never read by combine.

    router_kernel<<<TOKENS, 64, 0, stream>>>(x, Wr, br, cnt, tok_e, tok_pos, tok_gate);
    gather_kernel<<<TOKENS, 256, 0, stream>>>(x, cnt, tok_e, tok_pos, tok_gate,
                                              Xg, grow, rowof);
    // GEMM1: [rows x 1024] @ W1[e]^T (fp32, fused cvt) -> silu -> H [rows x 4096]
    gemm_kernel<0><<<dim3(32, F_DIM / 128, E_NUM), 256, 0, stream>>>(
        Xg, W1, b1, cnt, nullptr, H, F_DIM, D_DIM);
    // GEMM2: [rows x 4096] @ W2[e]^T (fp32, fused cvt) -> gate -> O [rows x 1024]
    gemm_kernel<1><<<dim3(32, D_DIM / 128, E_NUM), 256, 0, stream>>>(
        H, W2, b2, cnt, grow, O, D_DIM, F_DIM);
    combine_kernel<<<TOKENS, 256, 0, stream>>>(O, rowof, y);
}

// Round 4
// 671.892 us; speedup vs baseline: 1.0394x; 1.0295x over previous
//
#include <hip/hip_runtime.h>
#include <math.h>

typedef unsigned short ushort_t;
typedef __attribute__((ext_vector_type(8))) short bf16x8;
typedef __attribute__((ext_vector_type(4))) float f32x4;

#define TOKENS   4096
#define D_DIM    1024
#define E_NUM    8
#define F_DIM    4096

#define GLDS16(gp, lp) __builtin_amdgcn_global_load_lds( \
    (const __attribute__((address_space(1))) unsigned int*)(gp), \
    (__attribute__((address_space(3))) unsigned int*)(lp), 16, 0, 0)

__device__ __forceinline__ ushort_t f2bf(float f) {
    union { float f; unsigned u; } v; v.f = f;
    unsigned r = v.u + 0x7FFFu + ((v.u >> 16) & 1u);   // RNE
    return (ushort_t)(r >> 16);
}

// ---------------- fp32 -> bf16 bulk convert (8 elems/thread) ----------------
// MODE 0: also zero cnt (block 0)      — runs before router
// MODE 1: also zero y rows (blocks<4096) — runs right before GEMM2's atomics
template <int MODE>
__global__ __launch_bounds__(256) void convert_kernel(
    const float* __restrict__ src, ushort_t* __restrict__ dst,
    int* __restrict__ cnt, float* __restrict__ y)
{
    if (MODE == 0) {
        if (blockIdx.x == 0 && threadIdx.x < E_NUM) cnt[threadIdx.x] = 0;
    } else {
        if (blockIdx.x < TOKENS) {
            float4 z = {0.f, 0.f, 0.f, 0.f};
            *(float4*)&y[(size_t)blockIdx.x * D_DIM + threadIdx.x * 4] = z;
        }
    }
    size_t i = ((size_t)blockIdx.x * 256 + threadIdx.x) * 8;
    float4 a = *(const float4*)(src + i);
    float4 b = *(const float4*)(src + i + 4);
    union { ushort_t u[8]; uint4 v; } t;
    t.u[0] = f2bf(a.x); t.u[1] = f2bf(a.y); t.u[2] = f2bf(a.z); t.u[3] = f2bf(a.w);
    t.u[4] = f2bf(b.x); t.u[5] = f2bf(b.y); t.u[6] = f2bf(b.z); t.u[7] = f2bf(b.w);
    *(uint4*)(dst + i) = t.v;
}

// ---------------- Router: logits -> top2 -> gates -> per-expert position ----
__global__ __launch_bounds__(64) void router_kernel(
    const float* __restrict__ x, const float* __restrict__ Wr,
    const float* __restrict__ br,
    int* __restrict__ cnt, int* __restrict__ tok_e, int* __restrict__ tok_pos,
    float* __restrict__ tok_gate)
{
    int t = blockIdx.x;
    int lane = threadIdx.x;
    const float* xrow = x + (size_t)t * D_DIM;
    float acc[E_NUM];
#pragma unroll
    for (int e = 0; e < E_NUM; e++) acc[e] = 0.f;
    for (int d = lane; d < D_DIM; d += 64) {
        float xv = xrow[d];
#pragma unroll
        for (int e = 0; e < E_NUM; e++)
            acc[e] += xv * Wr[e * D_DIM + d];
    }
#pragma unroll
    for (int e = 0; e < E_NUM; e++) {
        float v = acc[e];
        for (int off = 32; off > 0; off >>= 1)
            v += __shfl_down(v, off, 64);
        acc[e] = v;
    }
    if (lane == 0) {
        float lg[E_NUM];
#pragma unroll
        for (int e = 0; e < E_NUM; e++) lg[e] = acc[e] + br[e];
        int e0 = 0;
#pragma unroll
        for (int e = 1; e < E_NUM; e++) if (lg[e] > lg[e0]) e0 = e;
        int e1 = (e0 == 0) ? 1 : 0;
#pragma unroll
        for (int e = 0; e < E_NUM; e++)
            if (e != e0 && lg[e] > lg[e1]) e1 = e;
        float g1 = expf(lg[e1] - lg[e0]);
        float denom = 1.f + g1;
        float gate0 = 1.f / denom, gate1 = g1 / denom;
        int p0 = atomicAdd(&cnt[e0], 1);
        int p1 = atomicAdd(&cnt[e1], 1);
        tok_e[t * 2] = e0;     tok_pos[t * 2] = p0;     tok_gate[t * 2] = gate0;
        tok_e[t * 2 + 1] = e1; tok_pos[t * 2 + 1] = p1; tok_gate[t * 2 + 1] = gate1;
    }
}

// ---------------- Gather x rows (fp32 -> bf16) into expert-compacted Xg -----
// One block per token: read the x row once, write both expert copies.
// Padded per-expert offsets recomputed inline from cnt (uniform scalar loop).
// Also writes row2tok (row -> source token) for GEMM2's fused combine.
__global__ __launch_bounds__(256) void gather_kernel(
    const float* __restrict__ x, const int* __restrict__ cnt,
    const int* __restrict__ tok_e, const int* __restrict__ tok_pos,
    const float* __restrict__ tok_gate,
    ushort_t* __restrict__ Xg, float* __restrict__ grow, int* __restrict__ row2tok)
{
    int t = blockIdx.x;
    int ea = tok_e[t * 2], eb = tok_e[t * 2 + 1];
    int off = 0, pa = 0, pb = 0;
#pragma unroll
    for (int q = 0; q < E_NUM; q++) {
        if (q == ea) pa = off;
        if (q == eb) pb = off;
        off += (cnt[q] + 127) & ~127;
    }
    int r0 = pa + tok_pos[t * 2];
    int r1 = pb + tok_pos[t * 2 + 1];
    if (threadIdx.x == 0) {
        grow[r0] = tok_gate[t * 2];     row2tok[r0] = t;
        grow[r1] = tok_gate[t * 2 + 1]; row2tok[r1] = t;
    }
    int i = threadIdx.x;                // 4 floats per thread
    float4 v = ((const float4*)(x + (size_t)t * D_DIM))[i];
    ushort4 o;
    o.x = f2bf(v.x); o.y = f2bf(v.y); o.z = f2bf(v.z); o.w = f2bf(v.w);
    *(ushort4*)(Xg + (size_t)r0 * D_DIM + i * 4) = o;
    *(ushort4*)(Xg + (size_t)r1 * D_DIM + i * 4) = o;
}

// ---------------- GEMM: C[m,n] = sum_k A[m,k]*B[n,k] (bf16, glds staging) ---
// R0-proven structure: single LDS buffer, 2 barriers/K-step, 4 blocks/CU.
// LDS layout is XOR-swizzled at the SOURCE: phys chunk c of row r holds global
// chunk c ^ (r&7). glds dest = wave-uniform base + lane*16 (m104/m108), so the
// swizzle must live in the global address, not the LDS address.
// ACT==0: H[row,n] = bf16(silu(C + b1[e,n])), all padded rows stored.
// ACT==1: fused combine — atomicAdd fp32 grow[row]*(C + b2[e,n]) into
//         y[row2tok[row]][n], guarded to REAL rows (pad rows are garbage).
template <int ACT>
__global__ __launch_bounds__(256, 4) void gemm_kernel(
    const ushort_t* __restrict__ A,   // bf16 rows, ld = K
    const ushort_t* __restrict__ Bw,  // [E][N][K] bf16
    const float* __restrict__ bias,   // [E][N]
    const int* __restrict__ cnt,
    const float* __restrict__ grow,
    ushort_t* __restrict__ Cout,      // ACT==0: bf16 rows, ld = N
    float* __restrict__ yout,         // ACT==1: [TOKENS][D_DIM] fp32
    const int* __restrict__ row2tok,  // ACT==1: row -> token
    int N, int K)
{
    __shared__ ushort_t As[128 * 64];
    __shared__ ushort_t Bs[128 * 64];

    int e = blockIdx.z;
    int mt = blockIdx.y;

    // padded per-expert offsets from cnt (uniform scalar loop)
    int rowstart = 0, pc = 0, creal = 0;
#pragma unroll
    for (int q = 0; q < E_NUM; q++) {
        int cq = cnt[q];
        int p = (cq + 127) & ~127;
        if (q < e) rowstart += p;
        if (q == e) { pc = p; creal = cq; }
    }
    if (mt * 128 >= pc) return;
    int rowbase = rowstart + mt * 128;
    int rowlim  = rowstart + creal;       // real (unpadded) row limit
    int nbase = blockIdx.x * 128;

    int tid = threadIdx.x;
    int wave = tid >> 6;
    int lane = tid & 63;
    int wm = (wave & 1) * 64;
    int wn = (wave >> 1) * 64;
    int quad = lane >> 4;
    int l16 = lane & 15;
    int fswz = l16 & 7;               // fragment-read swizzle key

    int srow = lane >> 3;             // 0..7 within an 8-row group
    int soff = ((lane & 7) ^ srow) * 8;  // swizzled source chunk (elems)

    f32x4 acc[4][4];
#pragma unroll
    for (int i = 0; i < 4; i++)
#pragma unroll
        for (int j = 0; j < 4; j++) {
            f32x4 z = {0.f, 0.f, 0.f, 0.f};
            acc[i][j] = z;
        }

    const ushort_t* Ag = A + (size_t)rowbase * K;
    const ushort_t* Bg = Bw + ((size_t)e * N + nbase) * K;

    for (int k0 = 0; k0 < K; k0 += 64) {
        __syncthreads();
#pragma unroll
        for (int it = 0; it < 4; it++) {
            int r = wave * 32 + it * 8;   // wave-uniform base row of 8-row group
            GLDS16(Ag + (size_t)(r + srow) * K + k0 + soff, &As[r * 64]);
            GLDS16(Bg + (size_t)(r + srow) * K + k0 + soff, &Bs[r * 64]);
        }
        __syncthreads();   // drains vmcnt(0) -> glds data visible
#pragma unroll
        for (int kk = 0; kk < 64; kk += 32) {
            int kc = kk >> 3;             // logical chunk base: 0 or 4
            bf16x8 af[4], bfr[4];
#pragma unroll
            for (int i = 0; i < 4; i++)
                af[i] = *(const bf16x8*)&As[(wm + i * 16 + l16) * 64 +
                                            (((quad + kc) ^ fswz) << 3)];
#pragma unroll
            for (int j = 0; j < 4; j++)
                bfr[j] = *(const bf16x8*)&Bs[(wn + j * 16 + l16) * 64 +
                                             (((quad + kc) ^ fswz) << 3)];
#pragma unroll
            for (int i = 0; i < 4; i++)
#pragma unroll
                for (int j = 0; j < 4; j++)
                    acc[i][j] = __builtin_amdgcn_mfma_f32_16x16x32_bf16(
                        af[i], bfr[j], acc[i][j], 0, 0, 0);
        }
    }

    // epilogue: D row = quad*4+r within 16-tile, col = l16
#pragma unroll
    for (int i = 0; i < 4; i++) {
#pragma unroll
        for (int j = 0; j < 4; j++) {
            int n = nbase + wn + j * 16 + l16;
            float bv = bias[(size_t)e * N + n];
#pragma unroll
            for (int r = 0; r < 4; r++) {
                int row = rowbase + wm + i * 16 + quad * 4 + r;
                float v = acc[i][j][r] + bv;
                if (ACT == 0) {
                    v = v / (1.f + __expf(-v));           // SiLU
                    Cout[(size_t)row * N + n] = f2bf(v);
                } else {
                    if (row < rowlim) {                   // real rows only
                        float vg = grow[row] * v;
                        atomicAdd(&yout[(size_t)row2tok[row] * N + n], vg);
                    }
                }
            }
        }
    }
}

extern "C" void kernel_launch(void* const* d_in, const int* in_sizes, int n_in,
                              void* d_out, int out_size, void* d_ws, size_t ws_size,
                              hipStream_t stream)
{
    (void)in_sizes; (void)n_in; (void)out_size; (void)ws_size;
    const float* x  = (const float*)d_in[0];
    const float* Wr = (const float*)d_in[1];
    const float* br = (const float*)d_in[2];
    const float* W1 = (const float*)d_in[3];
    const float* b1 = (const float*)d_in[4];
    const float* W2 = (const float*)d_in[5];
    const float* b2 = (const float*)d_in[6];
    float* y = (float*)d_out;

    char* ws = (char*)d_ws;
    int*   cnt      = (int*)(ws + 0);        // 8 ints
    int*   tok_e    = (int*)(ws + 128);      // 8192 ints
    int*   tok_pos  = (int*)(ws + 32896);    // 8192 ints
    float* tok_gate = (float*)(ws + 65664);  // 8192 floats
    int*   row2tok  = (int*)(ws + 98432);    // 9216 ints
    float* grow     = (float*)(ws + 136192); // 9216 floats
    // big buffers (256 KiB aligned start)
    ushort_t* Xg = (ushort_t*)(ws + 262144);                 // 9216x1024 bf16 (18,874,368 B)
    ushort_t* H  = (ushort_t*)(ws + 262144 + 18874368ull);   // 9216x4096 bf16 (75,497,472 B)
    ushort_t* Wb = (ushort_t*)(ws + 262144 + 18874368ull + 75497472ull); // 67,108,864 B, W1 then W2

    // 6 dispatches/iteration (was 10): conv1(+cnt=0), router, gather,
    // gemm1, conv2(+y=0), gemm2(+fused combine via fp32 atomics).
    convert_kernel<0><<<16384, 256, 0, stream>>>(W1, Wb, cnt, nullptr);
    router_kernel<<<TOKENS, 64, 0, stream>>>(x, Wr, br, cnt, tok_e, tok_pos, tok_gate);
    gather_kernel<<<TOKENS, 256, 0, stream>>>(x, cnt, tok_e, tok_pos, tok_gate,
                                              Xg, grow, row2tok);
    // GEMM1: [rows x 1024] @ W1[e]^T -> silu -> H [rows x 4096]
    gemm_kernel<0><<<dim3(F_DIM / 128, 32, E_NUM), 256, 0, stream>>>(
        Xg, Wb, b1, cnt, nullptr, H, nullptr, nullptr, F_DIM, D_DIM);
    // W2 -> bf16 (same buffer) + zero y
    convert_kernel<1><<<16384, 256, 0, stream>>>(W2, Wb, nullptr, y);
    // GEMM2: [rows x 4096] @ W2[e]^T -> gate -> atomicAdd into y
    gemm_kernel<1><<<dim3(D_DIM / 128, 32, E_NUM), 256, 0, stream>>>(
        H, Wb, b2, cnt, grow, nullptr, y, row2tok, D_DIM, F_DIM);
}